// Round 7
// baseline (440.814 us; speedup 1.0000x reference)
//
#include <hip/hip_runtime.h>
#include <stdint.h>

typedef unsigned short u16;
typedef __attribute__((ext_vector_type(8))) short short8;
typedef __attribute__((ext_vector_type(4))) short short4v;
typedef __attribute__((ext_vector_type(4))) float f32x4;

#define MFMA16(a, b, c) __builtin_amdgcn_mfma_f32_16x16x16bf16_1k(a, b, c, 0, 0, 0)
#define MFMA32(a, b, c) __builtin_amdgcn_mfma_f32_16x16x32_bf16(a, b, c, 0, 0, 0)

#if __has_builtin(__builtin_amdgcn_exp2f)
#define EXP2F(x) __builtin_amdgcn_exp2f(x)
#else
#define EXP2F(x) exp2f(x)   // host-pass fallback only
#endif

// async global->LDS DMA, 16B per lane; dst must be base+lane*16 contiguous per wave
#define ASYNC16(G, L)                                                            \
    __builtin_amdgcn_global_load_lds((const __attribute__((address_space(1))) void*)(const void*)(G), \
                                     (__attribute__((address_space(3))) void*)(void*)(L), 16, 0, 0)

__device__ __forceinline__ u16 f2bf(float f) {
    union { float f; uint32_t u; } c; c.f = f;
    uint32_t r = (c.u + 0x7fffu + ((c.u >> 16) & 1u)) >> 16;
    return (u16)r;
}

// ---------------- convert X (fp32 -> bf16) ----------------
__global__ __launch_bounds__(256) void k_convert_x(const float* __restrict__ X, u16* __restrict__ Xb) {
    int idx = blockIdx.x * 256 + threadIdx.x;
    float4 v = ((const float4*)X)[idx];
    union { u16 s[4]; uint2 v; } u;
    u.s[0] = f2bf(v.x); u.s[1] = f2bf(v.y); u.s[2] = f2bf(v.z); u.s[3] = f2bf(v.w);
    ((uint2*)Xb)[idx] = u.v;
}

// ---------------- convert + transpose the 4 weight matrices -> W^T bf16 (n-major) ----------------
__global__ __launch_bounds__(256) void k_convert_w(const float* __restrict__ W0, const float* __restrict__ W1,
                                                   const float* __restrict__ W2, const float* __restrict__ W3,
                                                   u16* __restrict__ Wt) {
    __shared__ u16 T[64][72];
    const float* W = (blockIdx.z == 0) ? W0 : (blockIdx.z == 1) ? W1 : (blockIdx.z == 2) ? W2 : W3;
    int k0 = blockIdx.x * 64, n0 = blockIdx.y * 64;
    int t = threadIdx.x;
    for (int i = 0; i < 4; i++) {
        int id = t + i * 256;
        int row = id >> 4, c4 = (id & 15) * 4;
        float4 v = *(const float4*)(W + (size_t)(k0 + row) * 512 + n0 + c4);
        union { u16 s[4]; uint2 v; } u;
        u.s[0] = f2bf(v.x); u.s[1] = f2bf(v.y); u.s[2] = f2bf(v.z); u.s[3] = f2bf(v.w);
        *(uint2*)&T[row][c4] = u.v;
    }
    __syncthreads();
    u16* O = Wt + (size_t)blockIdx.z * 512 * 512;
    for (int i = 0; i < 2; i++) {
        int id = t + i * 256;
        int row = id >> 3, c8 = (id & 7) * 8;
        union { u16 s[8]; uint4 v; } tmp;
        for (int j = 0; j < 8; j++) tmp.s[j] = T[c8 + j][row];
        *(uint4*)(O + (size_t)(n0 + row) * 512 + k0 + c8) = tmp.v;
    }
}

// ---------------- QKV projection GEMM ----------------
__global__ __launch_bounds__(256) void k_gemm_qkv(const u16* __restrict__ X, const u16* __restrict__ Wt,
                                                  u16* __restrict__ Q, u16* __restrict__ K, u16* __restrict__ V) {
    __shared__ u16 As[128][40];
    __shared__ u16 Bs[128][40];
    const int t = threadIdx.x;
    const int wave = t >> 6, lane = t & 63, quad = lane >> 4, l16 = lane & 15;
    const int wm = (wave >> 1) * 64, wn = (wave & 1) * 64;
    const int m0 = blockIdx.x * 128, n0 = blockIdx.y * 128;
    const u16* Bt = Wt + (size_t)blockIdx.z * 262144;
    const f32x4 fz = {0.f, 0.f, 0.f, 0.f};
    f32x4 acc[4][4];
    for (int i = 0; i < 4; i++) for (int j = 0; j < 4; j++) acc[i][j] = fz;
    for (int k0 = 0; k0 < 512; k0 += 32) {
        __syncthreads();
        for (int i = 0; i < 2; i++) {
            int id = t + i * 256;
            int row = id >> 2, c8 = (id & 3) * 8;
            *(uint4*)&As[row][c8] = *(const uint4*)(X + (size_t)(m0 + row) * 512 + k0 + c8);
            *(uint4*)&Bs[row][c8] = *(const uint4*)(Bt + (size_t)(n0 + row) * 512 + k0 + c8);
        }
        __syncthreads();
        short8 af[4], bf[4];
        for (int mt = 0; mt < 4; mt++) af[mt] = *(const short8*)&As[wm + mt * 16 + l16][quad * 8];
        for (int nt = 0; nt < 4; nt++) bf[nt] = *(const short8*)&Bs[wn + nt * 16 + l16][quad * 8];
        for (int mt = 0; mt < 4; mt++)
            for (int nt = 0; nt < 4; nt++)
                acc[mt][nt] = MFMA32(af[mt], bf[nt], acc[mt][nt]);
    }
    const float scale = (blockIdx.z == 0) ? 0.18033688011112042f : 1.0f;   // (1/8)*log2(e) for Q
    u16* Out = (blockIdx.z == 0) ? Q : (blockIdx.z == 1) ? K : V;
    for (int mt = 0; mt < 4; mt++)
        for (int nt = 0; nt < 4; nt++)
            for (int r = 0; r < 4; r++) {
                int m = m0 + wm + mt * 16 + quad * 4 + r;
                int n = n0 + wn + nt * 16 + l16;
                int b = m >> 13, s = m & 8191, h = n >> 6, d = n & 63;
                Out[((size_t)((b * 8 + h) * 8192 + s)) * 64 + d] = f2bf(acc[mt][nt][r] * scale);
            }
}

// ---------------- V (bh,s,d) -> Vt (bh,d,s) ----------------
__global__ __launch_bounds__(256) void k_transpose_v(const u16* __restrict__ V, u16* __restrict__ Vt) {
    __shared__ u16 T[64][72];
    int s0 = blockIdx.x * 64, bh = blockIdx.y;
    int t = threadIdx.x;
    for (int i = 0; i < 2; i++) {
        int id = t + i * 256, row = id >> 3, c8 = (id & 7) * 8;
        *(uint4*)&T[row][c8] = *(const uint4*)(V + ((size_t)bh * 8192 + s0 + row) * 64 + c8);
    }
    __syncthreads();
    for (int i = 0; i < 2; i++) {
        int id = t + i * 256, row = id >> 3, c8 = (id & 7) * 8;
        union { u16 s[8]; uint4 v; } tmp;
        for (int j = 0; j < 8; j++) tmp.s[j] = T[c8 + j][row];
        *(uint4*)(Vt + ((size_t)bh * 64 + row) * 8192 + s0 + c8) = tmp.v;
    }
}

// ---------------- flash attention: 64 q-rows/wave to halve LDS reads per MFMA ----------------
// R6 analysis: the LDS pipe was the bottleneck (reads 590k + conflicts 131k + writes 49k
// ~= whole wall per CU) because all waves read identical K/V fragments. Doubling the
// per-wave q-tile (64 rows, 4 m-tiles) halves LDS reads per MFMA. 256-thread blocks,
// BQ=256, 2 blocks/CU. Grid is (bh, qblk) so linear id % 8 clusters all q-blocks of a
// head-batch on one XCD (2 bh x 2MB K/V fits the 4MB L2). Shift-free softmax as before.
__global__ __launch_bounds__(256, 2) void k_flash(const u16* __restrict__ Q, const u16* __restrict__ K,
                                                  const u16* __restrict__ Vt, u16* __restrict__ Attn) {
    __shared__ u16 KsAll[2][4096];   // [buf][row*64 + chunk-swizzled cols]
    __shared__ u16 VsAll[2][4096];   // [buf][d*64 + chunk-swizzled keys]
    const int t = threadIdx.x;
    const int wave = t >> 6, lane = t & 63, quad = lane >> 4, l16 = lane & 15;
    const int l7 = l16 & 7, q1 = quad >> 1, qlo = quad & 1;
    const int bh = blockIdx.x, qblk = blockIdx.y;
    const int b = bh >> 3, h = bh & 7;
    const int q0g = qblk * 256;
    const int mq = wave * 64;
    const u16* Qb = Q + ((size_t)bh * 8192 + q0g) * 64;
    const u16* Kb = K + (size_t)bh * 8192 * 64;
    const u16* Vb = Vt + (size_t)bh * 64 * 8192;

    // DMA: 256 threads x 2 chunks x 16B per tile; thread t <-> chunks t, t+256
    const int r0 = t >> 3, r1 = (t + 256) >> 3;
    const int x0 = ((t & 7) ^ (r0 & 7)) * 8;
    const int x1 = ((t & 7) ^ (r1 & 7)) * 8;
    const u16* gK0 = Kb + r0 * 64 + x0;
    const u16* gK1 = Kb + r1 * 64 + x1;
    const u16* gV0 = Vb + (size_t)r0 * 8192 + x0;
    const u16* gV1 = Vb + (size_t)r1 * 8192 + x1;
    u16* lK = &KsAll[0][0] + t * 8;
    u16* lV = &VsAll[0][0] + t * 8;

    auto prefetch = [&](int it, int buf) {
        ASYNC16(gK0 + it * 4096, lK + buf * 4096);
        ASYNC16(gK1 + it * 4096, lK + buf * 4096 + 2048);
        ASYNC16(gV0 + it * 64,   lV + buf * 4096);
        ASYNC16(gV1 + it * 64,   lV + buf * 4096 + 2048);
    };

    // Q fragments (B-operand of S^T mfma): loop-invariant, 4 m-tiles
    short8 qf[4][2];
    for (int mt = 0; mt < 4; mt++)
        for (int ks = 0; ks < 2; ks++)
            qf[mt][ks] = *(const short8*)(Qb + (size_t)(mq + mt * 16 + l16) * 64 + ks * 32 + quad * 8);

    const f32x4 fz = {0.f, 0.f, 0.f, 0.f};
    f32x4 o[4][4];
    float l_i[4] = {0.f, 0.f, 0.f, 0.f};   // lane-local partial row sums (q=l16)
    for (int mt = 0; mt < 4; mt++) for (int nt = 0; nt < 4; nt++) o[mt][nt] = fz;

    prefetch(0, 0);

    auto body = [&](int it, int buf) {
        __syncthreads();                       // drains prefetch(it) (issued one body ago)
        if (it != 127) prefetch(it + 1, buf ^ 1);
        const u16* KsB = &KsAll[buf][0];
        const u16* VsB = &VsAll[buf][0];

        // S^T then exp+pack per (kt): sc is transient (keeps VGPR peak low)
        short4v pf[4][4];
        for (int kt = 0; kt < 4; kt++) {
            short8 kf0 = *(const short8*)(KsB + kt * 1024 + l16 * 64 + (((0 * 4 + quad) ^ l7) * 8));
            short8 kf1 = *(const short8*)(KsB + kt * 1024 + l16 * 64 + (((1 * 4 + quad) ^ l7) * 8));
            for (int mt = 0; mt < 4; mt++) {
                f32x4 sc = MFMA32(kf0, qf[mt][0], fz);
                sc = MFMA32(kf1, qf[mt][1], sc);
                union { float f; uint32_t u; } e0, e1, e2, e3;
                e0.f = EXP2F(sc[0]);
                e1.f = EXP2F(sc[1]);
                e2.f = EXP2F(sc[2]);
                e3.f = EXP2F(sc[3]);
                l_i[mt] += (e0.f + e1.f) + (e2.f + e3.f);
                union { uint32_t u[2]; short4v s; } pk;
                pk.u[0] = __builtin_amdgcn_perm(e1.u, e0.u, 0x07060302);
                pk.u[1] = __builtin_amdgcn_perm(e3.u, e2.u, 0x07060302);
                pf[mt][kt] = pk.s;
            }
        }

        // O += P V from registers; each vf read serves 4 m-tiles
        for (int kt = 0; kt < 4; kt++)
            for (int nt = 0; nt < 4; nt++) {
                short4v vf = *(const short4v*)(VsB + nt * 1024 + l16 * 64 + (((kt * 2 + q1) ^ l7) * 8) + qlo * 4);
                o[0][nt] = MFMA16(pf[0][kt], vf, o[0][nt]);
                o[1][nt] = MFMA16(pf[1][kt], vf, o[1][nt]);
                o[2][nt] = MFMA16(pf[2][kt], vf, o[2][nt]);
                o[3][nt] = MFMA16(pf[3][kt], vf, o[3][nt]);
            }
    };

    for (int it2 = 0; it2 < 64; it2++) {
        body(2 * it2, 0);
        body(2 * it2 + 1, 1);
    }

    // epilogue: finish l reduction (cross-quad) once, convert to C layout, write
    for (int mt = 0; mt < 4; mt++) {
        float l = l_i[mt];
        l += __shfl_xor(l, 16);
        l += __shfl_xor(l, 32);          // full row sum for q=l16, replicated across quads
        float inv = 1.0f / l;
        float invC[4];
        for (int r = 0; r < 4; r++) invC[r] = __shfl(inv, quad * 4 + r);   // q = quad*4+r
        for (int nt = 0; nt < 4; nt++)
            for (int r = 0; r < 4; r++) {
                int sg = q0g + mq + mt * 16 + quad * 4 + r;
                int n = h * 64 + nt * 16 + l16;
                Attn[((size_t)(b * 8192 + sg)) * 512 + n] = f2bf(o[mt][nt][r] * invC[r]);
            }
    }
}

// ---------------- output projection: Out = Attn @ Wo + b, fp32 ----------------
__global__ __launch_bounds__(256) void k_gemm_out(const u16* __restrict__ A, const u16* __restrict__ Wot,
                                                  const float* __restrict__ bias, float* __restrict__ Out) {
    __shared__ u16 As[128][40];
    __shared__ u16 Bs[128][40];
    const int t = threadIdx.x;
    const int wave = t >> 6, lane = t & 63, quad = lane >> 4, l16 = lane & 15;
    const int wm = (wave >> 1) * 64, wn = (wave & 1) * 64;
    const int m0 = blockIdx.x * 128, n0 = blockIdx.y * 128;
    const f32x4 fz = {0.f, 0.f, 0.f, 0.f};
    f32x4 acc[4][4];
    for (int i = 0; i < 4; i++) for (int j = 0; j < 4; j++) acc[i][j] = fz;
    for (int k0 = 0; k0 < 512; k0 += 32) {
        __syncthreads();
        for (int i = 0; i < 2; i++) {
            int id = t + i * 256;
            int row = id >> 2, c8 = (id & 3) * 8;
            *(uint4*)&As[row][c8] = *(const uint4*)(A + (size_t)(m0 + row) * 512 + k0 + c8);
            *(uint4*)&Bs[row][c8] = *(const uint4*)(Wot + (size_t)(n0 + row) * 512 + k0 + c8);
        }
        __syncthreads();
        short8 af[4], bf[4];
        for (int mt = 0; mt < 4; mt++) af[mt] = *(const short8*)&As[wm + mt * 16 + l16][quad * 8];
        for (int nt = 0; nt < 4; nt++) bf[nt] = *(const short8*)&Bs[wn + nt * 16 + l16][quad * 8];
        for (int mt = 0; mt < 4; mt++)
            for (int nt = 0; nt < 4; nt++)
                acc[mt][nt] = MFMA32(af[mt], bf[nt], acc[mt][nt]);
    }
    float bv[4];
    for (int nt = 0; nt < 4; nt++) bv[nt] = bias[n0 + wn + nt * 16 + l16];
    for (int mt = 0; mt < 4; mt++)
        for (int nt = 0; nt < 4; nt++)
            for (int r = 0; r < 4; r++) {
                int m = m0 + wm + mt * 16 + quad * 4 + r;
                int n = n0 + wn + nt * 16 + l16;
                Out[(size_t)m * 512 + n] = acc[mt][nt][r] + bv[nt];
            }
}

extern "C" void kernel_launch(void* const* d_in, const int* in_sizes, int n_in,
                              void* d_out, int out_size, void* d_ws, size_t ws_size,
                              hipStream_t stream) {
    const float* X   = (const float*)d_in[0];
    const float* w_q = (const float*)d_in[1];
    const float* w_k = (const float*)d_in[2];
    const float* w_v = (const float*)d_in[3];
    const float* w_o = (const float*)d_in[4];
    const float* b_o = (const float*)d_in[5];
    float* Out = (float*)d_out;

    char* ws = (char*)d_ws;
    u16* Xb   = (u16*)(ws);                 // 16 MiB  (reused as Attn after QKV GEMM)
    u16* Wt   = (u16*)(ws + 16777216);      //  2 MiB
    u16* Qd   = (u16*)(ws + 18874368);      // 16 MiB  (bh,s,d)
    u16* Kd   = (u16*)(ws + 35651584);      // 16 MiB  (bh,s,d)
    u16* Vd   = (u16*)(ws + 52428800);      // 16 MiB  (bh,s,d)
    u16* Vtd  = (u16*)(ws + 69206016);      // 16 MiB  (bh,d,s)
    u16* Attn = Xb;

    hipLaunchKernelGGL(k_convert_x, dim3(8192), dim3(256), 0, stream, X, Xb);
    hipLaunchKernelGGL(k_convert_w, dim3(8, 8, 4), dim3(256), 0, stream, w_q, w_k, w_v, w_o, Wt);
    hipLaunchKernelGGL(k_gemm_qkv, dim3(128, 4, 3), dim3(256), 0, stream, Xb, Wt, Qd, Kd, Vd);
    hipLaunchKernelGGL(k_transpose_v, dim3(128, 16), dim3(256), 0, stream, Vd, Vtd);
    hipLaunchKernelGGL(k_flash, dim3(16, 32), dim3(256), 0, stream, Qd, Kd, Vtd, Attn);
    hipLaunchKernelGGL(k_gemm_out, dim3(128, 4), dim3(256), 0, stream, Attn, Wt + 3 * 262144, b_o, Out);
}